// Round 2
// baseline (480.227 us; speedup 1.0000x reference)
//
#include <hip/hip_runtime.h>
#include <hip/hip_bf16.h>
#include <stdint.h>

#define T_SEQ 4096
#define C_DIM 2048
#define H_DIM 128
#define NBATCH 4

typedef unsigned short u16;
typedef __attribute__((ext_vector_type(8))) __bf16 bf16x8;
typedef __attribute__((ext_vector_type(4))) float f32x4;
typedef __attribute__((ext_vector_type(4))) unsigned short u16x4;

__device__ __forceinline__ u16 f2bf(float f) {
  union { float f; uint32_t i; } v; v.f = f;
  uint32_t r = v.i + 0x7FFFu + ((v.i >> 16) & 1u);
  return (u16)(r >> 16);
}

__device__ __forceinline__ void gload16(const void* g, void* l) {
  __builtin_amdgcn_global_load_lds(
      (__attribute__((address_space(1))) void*)(g),
      (__attribute__((address_space(3))) void*)(l), 16, 0, 0);
}

__device__ __forceinline__ f32x4 mfma_bf16(bf16x8 a, bf16x8 b, f32x4 c) {
  return __builtin_amdgcn_mfma_f32_16x16x32_bf16(a, b, c, 0, 0, 0);
}

// ---------------------------------------------------------------------------
// Kernel 1: W fp32 [2048][128] -> Wt bf16 [p][128][2048], p = {q,k,v}
// ---------------------------------------------------------------------------
__global__ void transpose_w(const float* __restrict__ Wq, const float* __restrict__ Wk,
                            const float* __restrict__ Wv, u16* __restrict__ Wt)
{
  int idx = blockIdx.x * 256 + threadIdx.x;          // 0 .. 3*128*2048-1
  int p   = idx >> 18;                               // 262144 = 2^18
  int rem = idx & 262143;
  int n   = rem >> 11;                               // 0..127
  int kk  = rem & 2047;                              // 0..2047
  const float* W = (p == 0) ? Wq : (p == 1) ? Wk : Wv;
  Wt[idx] = f2bf(W[kk * H_DIM + n]);
}

// ---------------------------------------------------------------------------
// Kernel 2: QKV projection GEMM. x fp32 [16384][2048], Wt bf16 [128][2048].
// 128x128 tile, BK=64, mfma 16x16x32 bf16. A: fp32 load + cvt + ds_write.
// B: global_load_lds 16B. p==0 q, p==1 k, p==2 v stored TRANSPOSED [b][d][t].
// ---------------------------------------------------------------------------
__global__ __launch_bounds__(256, 2) void qkv_gemm(
    const float* __restrict__ x, const u16* __restrict__ Wt,
    const float* __restrict__ bq, const float* __restrict__ bk, const float* __restrict__ bv,
    u16* __restrict__ qo, u16* __restrict__ ko, u16* __restrict__ vTo)
{
  __shared__ alignas(16) u16 As[128 * 64];
  __shared__ alignas(16) u16 Bs[128 * 64];

  const int tid  = threadIdx.x;
  const int w    = tid >> 6, lane = tid & 63;
  const int t16  = lane & 15, quad = lane >> 4;
  const int wr   = w >> 1, wc = w & 1;
  const int rt   = blockIdx.x;   // 0..127 row tiles
  const int p    = blockIdx.y;   // 0 q, 1 k, 2 v

  const u16*  Wp = Wt + (size_t)p * (H_DIM * C_DIM);
  const float* bp = (p == 0) ? bq : (p == 1) ? bk : bv;

  f32x4 acc[4][4];
  for (int i = 0; i < 4; ++i)
    for (int j = 0; j < 4; ++j) acc[i][j] = f32x4{0.f, 0.f, 0.f, 0.f};

  const size_t rowBase = (size_t)rt * 128;
  const int arow = tid >> 4;      // 0..15
  const int acl  = tid & 15;      // 0..15 (float4 cluster within 64-wide K)

  for (int k0 = 0; k0 < C_DIM; k0 += 64) {
    __syncthreads();
    // B tile: bf16 Wt via async 16B loads
    for (int j = 0; j < 4; ++j) {
      int e8 = (((j << 2) + w) * 64 + lane) * 8;   // element offset in 128x64 tile
      int rr = e8 >> 6, kk = e8 & 63;
      gload16(Wp + (size_t)rr * C_DIM + k0 + kk, &Bs[e8]);
    }
    // A tile: fp32 x -> bf16 LDS
    for (int pass = 0; pass < 8; ++pass) {
      int row = pass * 16 + arow;
      const float4 xv = *reinterpret_cast<const float4*>(
          &x[(rowBase + row) * C_DIM + k0 + acl * 4]);
      u16x4 pk;
      pk.x = f2bf(xv.x); pk.y = f2bf(xv.y); pk.z = f2bf(xv.z); pk.w = f2bf(xv.w);
      *reinterpret_cast<u16x4*>(&As[row * 64 + acl * 4]) = pk;
    }
    __syncthreads();
    for (int ks = 0; ks < 2; ++ks) {
      const int kof = ks * 32 + quad * 8;
      bf16x8 af[4], bfr[4];
      for (int ra = 0; ra < 4; ++ra)
        af[ra] = *(const bf16x8*)&As[(wr * 64 + ra * 16 + t16) * 64 + kof];
      for (int cb = 0; cb < 4; ++cb)
        bfr[cb] = *(const bf16x8*)&Bs[(wc * 64 + cb * 16 + t16) * 64 + kof];
      for (int ra = 0; ra < 4; ++ra)
        for (int cb = 0; cb < 4; ++cb)
          acc[ra][cb] = mfma_bf16(af[ra], bfr[cb], acc[ra][cb]);
    }
  }

  // Epilogue: C layout col = lane&15, row = quad*4 + r
  for (int cb = 0; cb < 4; ++cb) {
    int col = wc * 64 + cb * 16 + t16;
    float bias = bp[col];
    for (int ra = 0; ra < 4; ++ra) {
      for (int r = 0; r < 4; ++r) {
        size_t row = rowBase + wr * 64 + ra * 16 + quad * 4 + r;
        float v = acc[ra][cb][r] + bias;
        if (p == 2) {
          int bb = (int)(row >> 12);          // batch (4096 rows/batch)
          int tl = (int)(row & 4095);
          vTo[((size_t)bb * H_DIM + col) * T_SEQ + tl] = f2bf(v);
        } else {
          u16* dst = (p == 0) ? qo : ko;
          dst[row * H_DIM + col] = f2bf(v);
        }
      }
    }
  }
}

// ---------------------------------------------------------------------------
// Kernel 3: causal flash attention. q,k bf16 [b][t][128], vT bf16 [b][128][t].
// BM = BN = 64. 4 waves, wave w owns Q rows [qt*64 + w*16, +16). fp32 out.
// ---------------------------------------------------------------------------
__global__ __launch_bounds__(256, 1) void flash_attn(
    const u16* __restrict__ q, const u16* __restrict__ k,
    const u16* __restrict__ vT, float* __restrict__ out)
{
  __shared__ alignas(16) u16 Kt[64 * 128];    // [key][d]   16 KB
  __shared__ alignas(16) u16 Vt[128 * 64];    // [d][key]   16 KB
  __shared__ alignas(16) u16 Ps[4 * 16 * 64]; // per-wave P scratch, 8 KB

  const int tid  = threadIdx.x;
  const int w    = tid >> 6, lane = tid & 63;
  const int t16  = lane & 15, quad = lane >> 4;

  const int bid = blockIdx.x;
  const int qt  = 63 - (bid >> 2);   // longest q-tiles first
  const int b   = bid & 3;

  const float SCALE = 0.022097086912079612f;   // 2048^-0.5
  const float L2E   = 1.4426950408889634f;

  // Q fragments (A operand: row m = lane&15, k = quad*8+j), kept in registers
  bf16x8 qf[4];
  {
    const u16* qrow = q + ((size_t)(b * T_SEQ + qt * 64 + w * 16 + t16)) * H_DIM;
    for (int c = 0; c < 4; ++c)
      qf[c] = *(const bf16x8*)(qrow + c * 32 + quad * 8);
  }

  f32x4 Oc[8];
  for (int i = 0; i < 8; ++i) Oc[i] = f32x4{0.f, 0.f, 0.f, 0.f};
  float mrow[4] = {-1e30f, -1e30f, -1e30f, -1e30f};
  float lrow[4] = {0.f, 0.f, 0.f, 0.f};

  const u16* kbase = k  + ((size_t)b * T_SEQ) * H_DIM;
  const u16* vbase = vT + ((size_t)b * H_DIM) * T_SEQ;

  for (int kt = 0; kt <= qt; ++kt) {
    __syncthreads();   // previous iter's LDS reads done before overwrite
    {
      const u16* kg = kbase + (size_t)(kt * 64) * H_DIM;   // contiguous 16 KB
      for (int j = 0; j < 4; ++j) {
        int e8 = (((j << 2) + w) * 64 + lane) * 8;
        gload16(kg + e8, &Kt[e8]);
        int d = e8 >> 6, kk = e8 & 63;
        gload16(vbase + (size_t)d * T_SEQ + kt * 64 + kk, &Vt[e8]);
      }
    }
    __syncthreads();   // drains vmcnt: staging complete

    // S = Q K^T  (B operand from Kt: B[k=d][n=key] = K[key][d])
    f32x4 S[4];
    for (int ct = 0; ct < 4; ++ct) S[ct] = f32x4{0.f, 0.f, 0.f, 0.f};
    for (int c = 0; c < 4; ++c) {
      for (int ct = 0; ct < 4; ++ct) {
        bf16x8 kf = *(const bf16x8*)&Kt[(ct * 16 + t16) * H_DIM + c * 32 + quad * 8];
        S[ct] = mfma_bf16(qf[c], kf, S[ct]);
      }
    }

    // scale + causal mask (only diagonal tile needs masking)
    const bool diag = (kt == qt);
    for (int ct = 0; ct < 4; ++ct)
      for (int r = 0; r < 4; ++r) {
        float s = S[ct][r] * SCALE;
        if (diag && (ct * 16 + t16 > w * 16 + quad * 4 + r)) s = -1e30f;
        S[ct][r] = s;
      }

    // online softmax; rows of this wave's S live in its quad (16 lanes)
    float alpha[4], mnew[4];
    for (int r = 0; r < 4; ++r) {
      float mx = fmaxf(fmaxf(S[0][r], S[1][r]), fmaxf(S[2][r], S[3][r]));
      for (int m = 1; m < 16; m <<= 1) mx = fmaxf(mx, __shfl_xor(mx, m, 64));
      mnew[r]  = fmaxf(mrow[r], mx);
      alpha[r] = exp2f((mrow[r] - mnew[r]) * L2E);
      mrow[r]  = mnew[r];
    }
    for (int r = 0; r < 4; ++r) {
      float s = 0.f;
      for (int ct = 0; ct < 4; ++ct) {
        float pv = exp2f((S[ct][r] - mnew[r]) * L2E);
        S[ct][r] = pv;
        s += pv;
      }
      for (int m = 1; m < 16; m <<= 1) s += __shfl_xor(s, m, 64);
      lrow[r] = lrow[r] * alpha[r] + s;
    }
    for (int dt = 0; dt < 8; ++dt)
      for (int r = 0; r < 4; ++r)
        Oc[dt][r] *= alpha[r];

    // P: C layout -> A layout via per-wave LDS roundtrip (m120 pattern)
    u16* pw = &Ps[w * 1024];
    for (int ct = 0; ct < 4; ++ct)
      for (int r = 0; r < 4; ++r)
        pw[(quad * 4 + r) * 64 + ct * 16 + t16] = f2bf(S[ct][r]);
    __asm__ volatile("s_waitcnt lgkmcnt(0)" ::: "memory");  // own-wave ds ordering

    // O += P V  (B operand from Vt: B[k=key][n=d] = V[key][d] = Vt[d][key])
    for (int ks = 0; ks < 2; ++ks) {
      bf16x8 pf = *(const bf16x8*)&pw[t16 * 64 + ks * 32 + quad * 8];
      for (int dt = 0; dt < 8; ++dt) {
        bf16x8 vf = *(const bf16x8*)&Vt[(dt * 16 + t16) * 64 + ks * 32 + quad * 8];
        Oc[dt] = mfma_bf16(pf, vf, Oc[dt]);
      }
    }
  }

  // epilogue: normalize and store fp32
  for (int r = 0; r < 4; ++r) {
    float inv = 1.0f / lrow[r];
    size_t row = (size_t)b * T_SEQ + qt * 64 + w * 16 + quad * 4 + r;
    for (int dt = 0; dt < 8; ++dt)
      out[row * H_DIM + dt * 16 + t16] = Oc[dt][r] * inv;
  }
}

// ---------------------------------------------------------------------------
extern "C" void kernel_launch(void* const* d_in, const int* in_sizes, int n_in,
                              void* d_out, int out_size, void* d_ws, size_t ws_size,
                              hipStream_t stream) {
  const float* x  = (const float*)d_in[0];
  const float* Wk = (const float*)d_in[1];
  const float* bk = (const float*)d_in[2];
  const float* Wq = (const float*)d_in[3];
  const float* bq = (const float*)d_in[4];
  const float* Wv = (const float*)d_in[5];
  const float* bv = (const float*)d_in[6];
  float* out = (float*)d_out;

  char* ws = (char*)d_ws;
  u16* qb  = (u16*)(ws);                 // 4 MB  [b][t][128] bf16
  u16* kb  = (u16*)(ws + 4194304);       // 4 MB  [b][t][128] bf16
  u16* vT  = (u16*)(ws + 8388608);       // 4 MB  [b][128][t] bf16
  u16* Wt  = (u16*)(ws + 12582912);      // 1.5 MB [3][128][2048] bf16

  hipLaunchKernelGGL(transpose_w, dim3(3072), dim3(256), 0, stream, Wq, Wk, Wv, Wt);
  hipLaunchKernelGGL(qkv_gemm, dim3(128, 3), dim3(256), 0, stream,
                     x, Wt, bq, bk, bv, qb, kb, vT);
  hipLaunchKernelGGL(flash_attn, dim3(256), dim3(256), 0, stream, qb, kb, vT, out);
}

// Round 3
// 461.119 us; speedup vs baseline: 1.0414x; 1.0414x over previous
//
#include <hip/hip_runtime.h>
#include <hip/hip_bf16.h>
#include <stdint.h>

#define T_SEQ 4096
#define C_DIM 2048
#define H_DIM 128
#define NBATCH 4

typedef unsigned short u16;
typedef __attribute__((ext_vector_type(8))) __bf16 bf16x8;
typedef __attribute__((ext_vector_type(4))) float f32x4;
typedef __attribute__((ext_vector_type(8))) unsigned short u16x8;

__device__ __forceinline__ u16 f2bf(float f) {
  union { float f; uint32_t i; } v; v.f = f;
  uint32_t r = v.i + 0x7FFFu + ((v.i >> 16) & 1u);
  return (u16)(r >> 16);
}

__device__ __forceinline__ void gload16(const void* g, void* l) {
  __builtin_amdgcn_global_load_lds(
      (__attribute__((address_space(1))) void*)(g),
      (__attribute__((address_space(3))) void*)(l), 16, 0, 0);
}

__device__ __forceinline__ f32x4 mfma_bf16(bf16x8 a, bf16x8 b, f32x4 c) {
  return __builtin_amdgcn_mfma_f32_16x16x32_bf16(a, b, c, 0, 0, 0);
}

// DPP row rotate (16-lane row) — reductions without touching LDS.
template<int CTRL>
__device__ __forceinline__ float dpp_mov(float x) {
  return __int_as_float(__builtin_amdgcn_mov_dpp(__float_as_int(x), CTRL, 0xF, 0xF, true));
}
__device__ __forceinline__ float red16_max(float v) {
  v = fmaxf(v, dpp_mov<0x121>(v));   // row_ror:1
  v = fmaxf(v, dpp_mov<0x122>(v));   // row_ror:2
  v = fmaxf(v, dpp_mov<0x124>(v));   // row_ror:4
  v = fmaxf(v, dpp_mov<0x128>(v));   // row_ror:8
  return v;
}
__device__ __forceinline__ float red16_sum(float v) {
  v += dpp_mov<0x121>(v);
  v += dpp_mov<0x122>(v);
  v += dpp_mov<0x124>(v);
  v += dpp_mov<0x128>(v);
  return v;
}

// ---------------------------------------------------------------------------
// Kernel 1: W fp32 [2048][128] -> Wt bf16 [p][n][k], PRE-SWIZZLED so that
// contiguous global_load_lds staging lands an XOR-swizzled (conflict-free)
// B-tile in LDS:  Wt[p][n][kc*64 + g*8 + j] = W[kc*64 + (g^(n&7))*8 + j][n]
// ---------------------------------------------------------------------------
__global__ __launch_bounds__(256) void transpose_w(
    const float* __restrict__ Wq, const float* __restrict__ Wk,
    const float* __restrict__ Wv, u16* __restrict__ Wt)
{
  __shared__ u16 Wl[64 * 72];
  const int bk = blockIdx.x;   // k-tile 0..31
  const int bn = blockIdx.y;   // n-tile 0..1
  const int p  = blockIdx.z;   // 0 q, 1 k, 2 v
  const float* W = (p == 0) ? Wq : (p == 1) ? Wk : Wv;
  const int t = threadIdx.x;

  for (int ps = 0; ps < 16; ++ps) {
    int e  = ps * 256 + t;
    int kk = e >> 6, nn = e & 63;
    Wl[kk * 72 + nn] = f2bf(W[(size_t)(bk * 64 + kk) * H_DIM + bn * 64 + nn]);
  }
  __syncthreads();
  for (int ps = 0; ps < 16; ++ps) {
    int o  = ps * 256 + t;
    int nl = o >> 6, kl = o & 63;
    int n  = bn * 64 + nl;
    int g  = kl >> 3, j = kl & 7;
    int ks = ((g ^ (n & 7)) << 3) | j;
    Wt[(size_t)p * (H_DIM * C_DIM) + (size_t)n * C_DIM + bk * 64 + kl] = Wl[ks * 72 + nl];
  }
}

// ---------------------------------------------------------------------------
// Kernel 2: QKV GEMM. x fp32 [16384][2048], Wt bf16 pre-swizzled.
// 128x128 tile, BK=64. A: fp32 load + cvt + swizzled ds_write_b128.
// B: global_load_lds (pre-swizzled global). Outputs:
//   p==0 q natural [t][d]; p==1 k d-swizzled [t][d']; p==2 vT key-swizzled.
// ---------------------------------------------------------------------------
__global__ __launch_bounds__(256, 2) void qkv_gemm(
    const float* __restrict__ x, const u16* __restrict__ Wt,
    const float* __restrict__ bq, const float* __restrict__ bk, const float* __restrict__ bv,
    u16* __restrict__ qo, u16* __restrict__ ko, u16* __restrict__ vTo)
{
  __shared__ alignas(16) u16 As[128 * 64];
  __shared__ alignas(16) u16 Bs[128 * 64];

  const int tid  = threadIdx.x;
  const int w    = tid >> 6, lane = tid & 63;
  const int t16  = lane & 15, quad = lane >> 4;
  const int wr   = w >> 1, wc = w & 1;
  const int rt   = blockIdx.x;
  const int p    = blockIdx.y;

  const u16*   Wp = Wt + (size_t)p * (H_DIM * C_DIM);
  const float* bp = (p == 0) ? bq : (p == 1) ? bk : bv;

  f32x4 acc[4][4];
  for (int i = 0; i < 4; ++i)
    for (int j = 0; j < 4; ++j) acc[i][j] = f32x4{0.f, 0.f, 0.f, 0.f};

  const size_t rowBase = (size_t)rt * 128;

  for (int k0 = 0; k0 < C_DIM; k0 += 64) {
    __syncthreads();
    // B tile: pre-swizzled global -> contiguous LDS (async 16B)
    for (int j = 0; j < 4; ++j) {
      int e8 = (((j << 2) + w) * 64 + lane) * 8;
      int rr = e8 >> 6, kk = e8 & 63;
      gload16(Wp + (size_t)rr * C_DIM + k0 + kk, &Bs[e8]);
    }
    // A tile: fp32 x -> bf16, XOR-swizzled ds_write_b128
    for (int ps = 0; ps < 4; ++ps) {
      int gidx = ps * 256 + tid;
      int row = gidx >> 3, g = gidx & 7;
      const float4* xp = (const float4*)&x[(rowBase + row) * C_DIM + k0 + g * 8];
      float4 a0 = xp[0], a1 = xp[1];
      u16x8 pk;
      pk[0] = f2bf(a0.x); pk[1] = f2bf(a0.y); pk[2] = f2bf(a0.z); pk[3] = f2bf(a0.w);
      pk[4] = f2bf(a1.x); pk[5] = f2bf(a1.y); pk[6] = f2bf(a1.z); pk[7] = f2bf(a1.w);
      *(u16x8*)&As[row * 64 + ((g ^ (row & 7)) << 3)] = pk;
    }
    __syncthreads();
    for (int ks = 0; ks < 2; ++ks) {
      bf16x8 af[4], bfr[4];
      for (int ra = 0; ra < 4; ++ra)
        af[ra] = *(const bf16x8*)&As[(wr * 64 + ra * 16 + t16) * 64 +
                                     (((ks * 4 + quad) ^ (t16 & 7)) << 3)];
      for (int cb = 0; cb < 4; ++cb)
        bfr[cb] = *(const bf16x8*)&Bs[(wc * 64 + cb * 16 + t16) * 64 +
                                      (((ks * 4 + quad) ^ (t16 & 7)) << 3)];
      for (int ra = 0; ra < 4; ++ra)
        for (int cb = 0; cb < 4; ++cb)
          acc[ra][cb] = mfma_bf16(af[ra], bfr[cb], acc[ra][cb]);
    }
  }

  // Epilogue: C layout col = lane&15, row = quad*4 + r
  for (int cb = 0; cb < 4; ++cb) {
    int col = wc * 64 + cb * 16 + t16;
    float bias = bp[col];
    for (int ra = 0; ra < 4; ++ra) {
      for (int r = 0; r < 4; ++r) {
        size_t row = rowBase + wr * 64 + ra * 16 + quad * 4 + r;
        float v = acc[ra][cb][r] + bias;
        if (p == 2) {
          int bb = (int)(row >> 12);
          int tl = (int)(row & 4095);
          int gk = (tl & 63) >> 3;
          int tswz = (tl & ~63) | ((gk ^ (col & 7)) << 3) | (tl & 7);
          vTo[((size_t)bb * H_DIM + col) * T_SEQ + tswz] = f2bf(v);
        } else if (p == 1) {
          int gd = col >> 3;
          int cswz = ((gd ^ ((int)row & 15)) << 3) | (col & 7);
          ko[row * H_DIM + cswz] = f2bf(v);
        } else {
          qo[row * H_DIM + col] = f2bf(v);
        }
      }
    }
  }
}

// ---------------------------------------------------------------------------
// Kernel 3: causal flash attention, swizzled LDS, optional key-split.
// q natural, k d-swizzled, vT key-swizzled (all bf16). Partials fp32.
// ---------------------------------------------------------------------------
__global__ __launch_bounds__(256, 2) void flash_attn(
    const u16* __restrict__ q, const u16* __restrict__ k,
    const u16* __restrict__ vT, float* __restrict__ out,
    float* __restrict__ Opart, float* __restrict__ MLpart, int split)
{
  __shared__ alignas(16) u16 Kt[64 * 128];    // swizzled [key][g^key&15]
  __shared__ alignas(16) u16 Vt[128 * 64];    // swizzled [d][gk^d&7]
  __shared__ alignas(16) u16 Ps[4 * 16 * 72]; // per-wave P scratch, stride 72

  const int tid  = threadIdx.x;
  const int w    = tid >> 6, lane = tid & 63;
  const int t16  = lane & 15, quad = lane >> 4;
  const int b    = blockIdx.y;

  int qt, kt0, ktn, slot;   // slot<0 => direct store
  if (split) {
    int bid = blockIdx.x;   // 0..95, heavy chunks first
    if (bid < 32)      { qt = 32 + bid; kt0 = 0;  ktn = 32;      slot = (b * 32 + bid) * 2; }
    else if (bid < 64) { qt = 95 - bid; kt0 = 32; ktn = qt - 31; slot = (b * 32 + (qt - 32)) * 2 + 1; }
    else               { qt = 95 - bid; kt0 = 0;  ktn = qt + 1;  slot = -1; }
  } else {
    qt = 63 - blockIdx.x; kt0 = 0; ktn = qt + 1; slot = -1;
  }

  const float SCALE = 0.022097086912079612f;   // 2048^-0.5
  const float L2E   = 1.4426950408889634f;

  bf16x8 qf[4];
  {
    const u16* qrow = q + ((size_t)(b * T_SEQ + qt * 64 + w * 16 + t16)) * H_DIM;
    for (int c = 0; c < 4; ++c)
      qf[c] = *(const bf16x8*)(qrow + c * 32 + quad * 8);
  }

  f32x4 Oc[8];
  for (int i = 0; i < 8; ++i) Oc[i] = f32x4{0.f, 0.f, 0.f, 0.f};
  float mrow[4] = {-1e30f, -1e30f, -1e30f, -1e30f};
  float lrow[4] = {0.f, 0.f, 0.f, 0.f};

  const u16* kbase = k  + ((size_t)b * T_SEQ) * H_DIM;
  const u16* vbase = vT + ((size_t)b * H_DIM) * T_SEQ;

  for (int it = 0; it < ktn; ++it) {
    const int kt = kt0 + it;
    __syncthreads();
    {
      const u16* kg = kbase + (size_t)(kt * 64) * H_DIM;   // contiguous 16 KB
      for (int j = 0; j < 4; ++j) {
        int e8 = (((j << 2) + w) * 64 + lane) * 8;
        gload16(kg + e8, &Kt[e8]);
        int d = e8 >> 6, kk = e8 & 63;
        gload16(vbase + (size_t)d * T_SEQ + kt * 64 + kk, &Vt[e8]);
      }
    }
    __syncthreads();

    // S = Q K^T (Kt read swizzled: granule (c*4+quad) ^ t16)
    f32x4 S[4];
    for (int ct = 0; ct < 4; ++ct) S[ct] = f32x4{0.f, 0.f, 0.f, 0.f};
    for (int c = 0; c < 4; ++c) {
      for (int ct = 0; ct < 4; ++ct) {
        bf16x8 kf = *(const bf16x8*)&Kt[(ct * 16 + t16) * H_DIM +
                                        (((c * 4 + quad) ^ t16) << 3)];
        S[ct] = mfma_bf16(qf[c], kf, S[ct]);
      }
    }

    const bool diag = (kt == qt);
    for (int ct = 0; ct < 4; ++ct)
      for (int r = 0; r < 4; ++r) {
        float s = S[ct][r] * SCALE;
        if (diag && (ct * 16 + t16 > w * 16 + quad * 4 + r)) s = -1e30f;
        S[ct][r] = s;
      }

    // online softmax (DPP reductions over the 16-lane row domain)
    float alpha[4], mnew[4];
    for (int r = 0; r < 4; ++r) {
      float mx = red16_max(fmaxf(fmaxf(S[0][r], S[1][r]), fmaxf(S[2][r], S[3][r])));
      mnew[r]  = fmaxf(mrow[r], mx);
      alpha[r] = exp2f((mrow[r] - mnew[r]) * L2E);
      mrow[r]  = mnew[r];
    }
    for (int r = 0; r < 4; ++r) {
      float s = 0.f;
      for (int ct = 0; ct < 4; ++ct) {
        float pv = exp2f((S[ct][r] - mnew[r]) * L2E);
        S[ct][r] = pv;
        s += pv;
      }
      lrow[r] = lrow[r] * alpha[r] + red16_sum(s);
    }
    for (int dt = 0; dt < 8; ++dt)
      for (int r = 0; r < 4; ++r)
        Oc[dt][r] *= alpha[r];

    // P: C layout -> A layout via padded per-wave LDS scratch
    u16* pw = &Ps[w * 1152];
    for (int ct = 0; ct < 4; ++ct)
      for (int r = 0; r < 4; ++r)
        pw[(quad * 4 + r) * 72 + ct * 16 + t16] = f2bf(S[ct][r]);
    __asm__ volatile("s_waitcnt lgkmcnt(0)" ::: "memory");

    // O += P V (Vt read swizzled: granule (ks*4+quad) ^ (t16&7))
    for (int ks = 0; ks < 2; ++ks) {
      bf16x8 pf = *(const bf16x8*)&pw[t16 * 72 + ks * 32 + quad * 8];
      for (int dt = 0; dt < 8; ++dt) {
        bf16x8 vf = *(const bf16x8*)&Vt[(dt * 16 + t16) * 64 +
                                        (((ks * 4 + quad) ^ (t16 & 7)) << 3)];
        Oc[dt] = mfma_bf16(pf, vf, Oc[dt]);
      }
    }
  }

  if (slot < 0) {
    for (int r = 0; r < 4; ++r) {
      float inv = 1.0f / lrow[r];
      size_t row = (size_t)b * T_SEQ + qt * 64 + w * 16 + quad * 4 + r;
      for (int dt = 0; dt < 8; ++dt)
        out[row * H_DIM + dt * 16 + t16] = Oc[dt][r] * inv;
    }
  } else {
    if (t16 == 0) {
      for (int r = 0; r < 4; ++r) {
        int row = w * 16 + quad * 4 + r;
        MLpart[(size_t)slot * 128 + row * 2 + 0] = mrow[r];
        MLpart[(size_t)slot * 128 + row * 2 + 1] = lrow[r];
      }
    }
    float* op = Opart + (size_t)slot * 8192;
    for (int r = 0; r < 4; ++r) {
      int row = w * 16 + quad * 4 + r;
      for (int dt = 0; dt < 8; ++dt)
        op[row * 128 + dt * 16 + t16] = Oc[dt][r];
    }
  }
}

// ---------------------------------------------------------------------------
// Kernel 4: merge the two key-chunks of each split (b, qt>=32) tile.
// ---------------------------------------------------------------------------
__global__ __launch_bounds__(256) void combine(
    const float* __restrict__ Opart, const float* __restrict__ MLpart,
    float* __restrict__ out)
{
  __shared__ float c1s[64], c2s[64];
  const float L2E = 1.4426950408889634f;
  const int s = blockIdx.x;           // 0..127
  const int b = s >> 5, qt = 32 + (s & 31);
  const int t = threadIdx.x;

  if (t < 64) {
    const float* ML1 = MLpart + (size_t)(s * 2) * 128;
    const float* ML2 = ML1 + 128;
    float m1 = ML1[t * 2], l1 = ML1[t * 2 + 1];
    float m2 = ML2[t * 2], l2 = ML2[t * 2 + 1];
    float m  = fmaxf(m1, m2);
    float e1 = exp2f((m1 - m) * L2E);
    float e2 = exp2f((m2 - m) * L2E);
    float inv = 1.0f / (l1 * e1 + l2 * e2);
    c1s[t] = e1 * inv; c2s[t] = e2 * inv;
  }
  __syncthreads();

  const float* O1 = Opart + (size_t)(s * 2) * 8192;
  const float* O2 = O1 + 8192;
  float* o = out + ((size_t)b * T_SEQ + qt * 64) * (size_t)H_DIM;
  for (int i = t; i < 8192; i += 256) {
    int row = i >> 7;
    o[i] = O1[i] * c1s[row] + O2[i] * c2s[row];
  }
}

// ---------------------------------------------------------------------------
extern "C" void kernel_launch(void* const* d_in, const int* in_sizes, int n_in,
                              void* d_out, int out_size, void* d_ws, size_t ws_size,
                              hipStream_t stream) {
  const float* x  = (const float*)d_in[0];
  const float* Wk = (const float*)d_in[1];
  const float* bk = (const float*)d_in[2];
  const float* Wq = (const float*)d_in[3];
  const float* bq = (const float*)d_in[4];
  const float* Wv = (const float*)d_in[5];
  const float* bv = (const float*)d_in[6];
  float* out = (float*)d_out;

  char* ws = (char*)d_ws;
  u16* qb  = (u16*)(ws);                       // 4 MB  [b][t][128] bf16
  u16* kb  = (u16*)(ws + 4194304);             // 4 MB  [b][t][d'] bf16 (swizzled)
  u16* vT  = (u16*)(ws + 8388608);             // 4 MB  [b][128][t'] bf16 (swizzled)
  u16* Wt  = (u16*)(ws + 12582912);            // 1.5 MB pre-swizzled weights
  float* Opart  = (float*)(ws + 14155776);     // 8 MB  256 x 64 x 128 fp32
  float* MLpart = (float*)(ws + 14155776 + 8388608);   // 128 KB

  const size_t need = 14155776ull + 8388608ull + 131072ull;
  const int split = (ws_size >= need) ? 1 : 0;

  hipLaunchKernelGGL(transpose_w, dim3(32, 2, 3), dim3(256), 0, stream, Wq, Wk, Wv, Wt);
  hipLaunchKernelGGL(qkv_gemm, dim3(128, 3), dim3(256), 0, stream,
                     x, Wt, bq, bk, bv, qb, kb, vT);
  hipLaunchKernelGGL(flash_attn, dim3(split ? 96 : 64, 4), dim3(256), 0, stream,
                     qb, kb, vT, out, Opart, MLpart, split);
  if (split)
    hipLaunchKernelGGL(combine, dim3(128), dim3(256), 0, stream, Opart, MLpart, out);
}

// Round 4
// 324.297 us; speedup vs baseline: 1.4808x; 1.4219x over previous
//
#include <hip/hip_runtime.h>
#include <hip/hip_bf16.h>
#include <stdint.h>

#define T_SEQ 4096
#define C_DIM 2048
#define H_DIM 128
#define NBATCH 4

typedef unsigned short u16;
typedef __attribute__((ext_vector_type(8))) __bf16 bf16x8;
typedef __attribute__((ext_vector_type(4))) float f32x4;
typedef __attribute__((ext_vector_type(8))) unsigned short u16x8;

__device__ __forceinline__ u16 f2bf(float f) {
  union { float f; uint32_t i; } v; v.f = f;
  uint32_t r = v.i + 0x7FFFu + ((v.i >> 16) & 1u);
  return (u16)(r >> 16);
}

__device__ __forceinline__ void gload16(const void* g, void* l) {
  __builtin_amdgcn_global_load_lds(
      (__attribute__((address_space(1))) void*)(g),
      (__attribute__((address_space(3))) void*)(l), 16, 0, 0);
}

__device__ __forceinline__ f32x4 mfma_bf16(bf16x8 a, bf16x8 b, f32x4 c) {
  return __builtin_amdgcn_mfma_f32_16x16x32_bf16(a, b, c, 0, 0, 0);
}

// DPP row rotate (16-lane row) reductions — no LDS traffic.
template<int CTRL>
__device__ __forceinline__ float dpp_mov(float x) {
  return __int_as_float(__builtin_amdgcn_mov_dpp(__float_as_int(x), CTRL, 0xF, 0xF, true));
}
__device__ __forceinline__ float red16_max(float v) {
  v = fmaxf(v, dpp_mov<0x121>(v));
  v = fmaxf(v, dpp_mov<0x122>(v));
  v = fmaxf(v, dpp_mov<0x124>(v));
  v = fmaxf(v, dpp_mov<0x128>(v));
  return v;
}
__device__ __forceinline__ float red16_sum(float v) {
  v += dpp_mov<0x121>(v);
  v += dpp_mov<0x122>(v);
  v += dpp_mov<0x124>(v);
  v += dpp_mov<0x128>(v);
  return v;
}

// ---------------------------------------------------------------------------
// Kernel 1: W fp32 [2048][128] -> Wt bf16 [p][n][k], pre-swizzled so that
// contiguous global_load_lds staging lands an XOR-swizzled B-tile in LDS.
// ---------------------------------------------------------------------------
__global__ __launch_bounds__(256) void transpose_w(
    const float* __restrict__ Wq, const float* __restrict__ Wk,
    const float* __restrict__ Wv, u16* __restrict__ Wt)
{
  __shared__ u16 Wl[64 * 72];
  const int bk = blockIdx.x;   // k-tile 0..31
  const int bn = blockIdx.y;   // n-tile 0..1
  const int p  = blockIdx.z;   // 0 q, 1 k, 2 v
  const float* W = (p == 0) ? Wq : (p == 1) ? Wk : Wv;
  const int t = threadIdx.x;

  for (int ps = 0; ps < 16; ++ps) {
    int e  = ps * 256 + t;
    int kk = e >> 6, nn = e & 63;
    Wl[kk * 72 + nn] = f2bf(W[(size_t)(bk * 64 + kk) * H_DIM + bn * 64 + nn]);
  }
  __syncthreads();
  for (int ps = 0; ps < 16; ++ps) {
    int o  = ps * 256 + t;
    int nl = o >> 6, kl = o & 63;
    int n  = bn * 64 + nl;
    int g  = kl >> 3, j = kl & 7;
    int ks = ((g ^ (n & 7)) << 3) | j;
    Wt[(size_t)p * (H_DIM * C_DIM) + (size_t)n * C_DIM + bk * 64 + kl] = Wl[ks * 72 + nl];
  }
}

// ---------------------------------------------------------------------------
// Kernel 2: QKV GEMM, 128x128 tile, BK=64, mfma 16x16x32 bf16.
// Epilogue stages the output tile in LDS and issues fully-coalesced 16B
// global stores (round-3 counters: 628 MB HBM writes from 2B scatter).
//   p==0 q natural [t][d]; p==1 k d-swizzled [t][d']; p==2 vT key-swizzled.
// ---------------------------------------------------------------------------
__global__ __launch_bounds__(256, 2) void qkv_gemm(
    const float* __restrict__ x, const u16* __restrict__ Wt,
    const float* __restrict__ bq, const float* __restrict__ bk, const float* __restrict__ bv,
    u16* __restrict__ qo, u16* __restrict__ ko, u16* __restrict__ vTo)
{
  __shared__ alignas(16) u16 SMEM[128 * 128];   // 32 KB: As|Bs in loop, C-tile in epilogue
  u16* As = SMEM;               // 128 x 64
  u16* Bs = SMEM + 128 * 64;    // 128 x 64

  const int tid  = threadIdx.x;
  const int w    = tid >> 6, lane = tid & 63;
  const int t16  = lane & 15, quad = lane >> 4;
  const int wr   = w >> 1, wc = w & 1;
  const int rt   = blockIdx.x;
  const int p    = blockIdx.y;

  const u16*   Wp = Wt + (size_t)p * (H_DIM * C_DIM);
  const float* bp = (p == 0) ? bq : (p == 1) ? bk : bv;

  f32x4 acc[4][4];
  for (int i = 0; i < 4; ++i)
    for (int j = 0; j < 4; ++j) acc[i][j] = f32x4{0.f, 0.f, 0.f, 0.f};

  const size_t rowBase = (size_t)rt * 128;

  for (int k0 = 0; k0 < C_DIM; k0 += 64) {
    __syncthreads();
    for (int j = 0; j < 4; ++j) {
      int e8 = (((j << 2) + w) * 64 + lane) * 8;
      int rr = e8 >> 6, kk = e8 & 63;
      gload16(Wp + (size_t)rr * C_DIM + k0 + kk, &Bs[e8]);
    }
    for (int ps = 0; ps < 4; ++ps) {
      int gidx = ps * 256 + tid;
      int row = gidx >> 3, g = gidx & 7;
      const float4* xp = (const float4*)&x[(rowBase + row) * C_DIM + k0 + g * 8];
      float4 a0 = xp[0], a1 = xp[1];
      u16x8 pk;
      pk[0] = f2bf(a0.x); pk[1] = f2bf(a0.y); pk[2] = f2bf(a0.z); pk[3] = f2bf(a0.w);
      pk[4] = f2bf(a1.x); pk[5] = f2bf(a1.y); pk[6] = f2bf(a1.z); pk[7] = f2bf(a1.w);
      *(u16x8*)&As[row * 64 + ((g ^ (row & 7)) << 3)] = pk;
    }
    __syncthreads();
    for (int ks = 0; ks < 2; ++ks) {
      bf16x8 af[4], bfr[4];
      for (int ra = 0; ra < 4; ++ra)
        af[ra] = *(const bf16x8*)&As[(wr * 64 + ra * 16 + t16) * 64 +
                                     (((ks * 4 + quad) ^ (t16 & 7)) << 3)];
      for (int cb = 0; cb < 4; ++cb)
        bfr[cb] = *(const bf16x8*)&Bs[(wc * 64 + cb * 16 + t16) * 64 +
                                      (((ks * 4 + quad) ^ (t16 & 7)) << 3)];
      for (int ra = 0; ra < 4; ++ra)
        for (int cb = 0; cb < 4; ++cb)
          acc[ra][cb] = mfma_bf16(af[ra], bfr[cb], acc[ra][cb]);
    }
  }

  // ---- epilogue: acc -> LDS tile (swizzled), then coalesced 16B stores ----
  __syncthreads();   // all K-loop LDS reads done before SMEM reuse
  for (int cb = 0; cb < 4; ++cb) {
    int col = wc * 64 + cb * 16 + t16;
    float bias = bp[col];
    for (int ra = 0; ra < 4; ++ra) {
      for (int r = 0; r < 4; ++r) {
        int row16 = wr * 64 + ra * 16 + quad * 4 + r;   // block-local t
        float v = acc[ra][cb][r] + bias;
        if (p == 2) {
          // store transposed: S[d=col][t swizzled]
          int swz = (row16 >> 3) ^ (col & 15);
          SMEM[col * 128 + (swz << 3) + (row16 & 7)] = f2bf(v);
        } else {
          // row-major, granule XOR-swizzled (== k's global layout for p==1)
          int g = col >> 3;
          SMEM[row16 * 128 + (((g ^ (row16 & 15)) << 3) | (col & 7))] = f2bf(v);
        }
      }
    }
  }
  __syncthreads();

  if (p == 1) {
    // LDS layout == global layout: flat 32 KB copy
    u16* kдst = ko + rowBase * H_DIM;
    for (int ps = 0; ps < 8; ++ps) {
      int c = ps * 256 + tid;      // 16B chunk id 0..2047
      *(u16x8*)&kдst[c * 8] = *(const u16x8*)&SMEM[c * 8];
    }
  } else if (p == 0) {
    for (int ps = 0; ps < 8; ++ps) {
      int c = ps * 256 + tid;
      int row16 = c >> 4, g = c & 15;
      u16x8 v = *(const u16x8*)&SMEM[row16 * 128 + ((g ^ (row16 & 15)) << 3)];
      *(u16x8*)&qo[(rowBase + row16) * H_DIM + g * 8] = v;
    }
  } else {
    const int bb = rt >> 5;            // batch
    const int tb = (rt & 31) * 128;    // t offset within batch
    for (int ps = 0; ps < 8; ++ps) {
      int c = ps * 256 + tid;
      int d = c >> 4, gt = c & 15;
      u16x8 v = *(const u16x8*)&SMEM[d * 128 + ((gt ^ (d & 15)) << 3)];
      int toff = tb + ((gt >> 3) << 6) + (((gt & 7) ^ (d & 7)) << 3);
      *(u16x8*)&vTo[((size_t)bb * H_DIM + d) * T_SEQ + toff] = v;
    }
  }
}

// ---------------------------------------------------------------------------
// Kernel 3: causal flash attention, double-buffered K/V staging, swizzled LDS.
// q natural, k d-swizzled, vT key-swizzled (bf16). Split-K partials fp32.
// ---------------------------------------------------------------------------
__global__ __launch_bounds__(256, 2) void flash_attn(
    const u16* __restrict__ q, const u16* __restrict__ k,
    const u16* __restrict__ vT, float* __restrict__ out,
    float* __restrict__ Opart, float* __restrict__ MLpart, int split)
{
  __shared__ alignas(16) u16 Kt[2][64 * 128];    // 2 x 16 KB
  __shared__ alignas(16) u16 Vt[2][128 * 64];    // 2 x 16 KB
  __shared__ alignas(16) u16 Ps[4 * 16 * 72];    // 9 KB

  const int tid  = threadIdx.x;
  const int w    = tid >> 6, lane = tid & 63;
  const int t16  = lane & 15, quad = lane >> 4;
  const int b    = blockIdx.x;

  int qt, kt0, ktn, slot;   // slot<0 => direct store
  if (split) {
    int bid = blockIdx.y;   // heavy chunks (all batches) dispatch first
    if (bid < 32)      { qt = 32 + bid; kt0 = 0;  ktn = 32;      slot = (b * 32 + bid) * 2; }
    else if (bid < 64) { qt = 95 - bid; kt0 = 32; ktn = qt - 31; slot = (b * 32 + (qt - 32)) * 2 + 1; }
    else               { qt = 95 - bid; kt0 = 0;  ktn = qt + 1;  slot = -1; }
  } else {
    qt = 63 - blockIdx.y; kt0 = 0; ktn = qt + 1; slot = -1;
  }

  const float SCALE = 0.022097086912079612f;   // 2048^-0.5
  const float L2E   = 1.4426950408889634f;

  bf16x8 qf[4];
  {
    const u16* qrow = q + ((size_t)(b * T_SEQ + qt * 64 + w * 16 + t16)) * H_DIM;
    for (int c = 0; c < 4; ++c)
      qf[c] = *(const bf16x8*)(qrow + c * 32 + quad * 8);
  }

  f32x4 Oc[8];
  for (int i = 0; i < 8; ++i) Oc[i] = f32x4{0.f, 0.f, 0.f, 0.f};
  float mrow[4] = {-1e30f, -1e30f, -1e30f, -1e30f};
  float lrow[4] = {0.f, 0.f, 0.f, 0.f};

  const u16* kbase = k  + ((size_t)b * T_SEQ) * H_DIM;
  const u16* vbase = vT + ((size_t)b * H_DIM) * T_SEQ;

  // prefetch first tile into buffer 0
  {
    const u16* kg = kbase + (size_t)(kt0 * 64) * H_DIM;
    for (int j = 0; j < 4; ++j) {
      int e8 = (((j << 2) + w) * 64 + lane) * 8;
      gload16(kg + e8, &Kt[0][e8]);
      int d = e8 >> 6, kk = e8 & 63;
      gload16(vbase + (size_t)d * T_SEQ + kt0 * 64 + kk, &Vt[0][e8]);
    }
  }

  int cur = 0;
  for (int it = 0; it < ktn; ++it) {
    const int kt = kt0 + it;
    __syncthreads();   // drains prefetch of `cur`; WAR-guard for next prefetch
    if (it + 1 < ktn) {
      const int nb = cur ^ 1, ktn1 = kt + 1;
      const u16* kg = kbase + (size_t)(ktn1 * 64) * H_DIM;
      for (int j = 0; j < 4; ++j) {
        int e8 = (((j << 2) + w) * 64 + lane) * 8;
        gload16(kg + e8, &Kt[nb][e8]);
        int d = e8 >> 6, kk = e8 & 63;
        gload16(vbase + (size_t)d * T_SEQ + ktn1 * 64 + kk, &Vt[nb][e8]);
      }
    }

    // S = Q K^T
    f32x4 S[4];
    for (int ct = 0; ct < 4; ++ct) S[ct] = f32x4{0.f, 0.f, 0.f, 0.f};
    for (int c = 0; c < 4; ++c) {
      for (int ct = 0; ct < 4; ++ct) {
        bf16x8 kf = *(const bf16x8*)&Kt[cur][(ct * 16 + t16) * H_DIM +
                                            (((c * 4 + quad) ^ t16) << 3)];
        S[ct] = mfma_bf16(qf[c], kf, S[ct]);
      }
    }

    const bool diag = (kt == qt);
    for (int ct = 0; ct < 4; ++ct)
      for (int r = 0; r < 4; ++r) {
        float s = S[ct][r] * SCALE;
        if (diag && (ct * 16 + t16 > w * 16 + quad * 4 + r)) s = -1e30f;
        S[ct][r] = s;
      }

    float alpha[4], mnew[4];
    for (int r = 0; r < 4; ++r) {
      float mx = red16_max(fmaxf(fmaxf(S[0][r], S[1][r]), fmaxf(S[2][r], S[3][r])));
      mnew[r]  = fmaxf(mrow[r], mx);
      alpha[r] = exp2f((mrow[r] - mnew[r]) * L2E);
      mrow[r]  = mnew[r];
    }
    for (int r = 0; r < 4; ++r) {
      float s = 0.f;
      for (int ct = 0; ct < 4; ++ct) {
        float pv = exp2f((S[ct][r] - mnew[r]) * L2E);
        S[ct][r] = pv;
        s += pv;
      }
      lrow[r] = lrow[r] * alpha[r] + red16_sum(s);
    }
    for (int dt = 0; dt < 8; ++dt)
      for (int r = 0; r < 4; ++r)
        Oc[dt][r] *= alpha[r];

    // P: C layout -> A layout via padded per-wave LDS scratch
    u16* pw = &Ps[w * 1152];
    for (int ct = 0; ct < 4; ++ct)
      for (int r = 0; r < 4; ++r)
        pw[(quad * 4 + r) * 72 + ct * 16 + t16] = f2bf(S[ct][r]);
    __asm__ volatile("s_waitcnt lgkmcnt(0)" ::: "memory");

    for (int ks = 0; ks < 2; ++ks) {
      bf16x8 pf = *(const bf16x8*)&pw[t16 * 72 + ks * 32 + quad * 8];
      for (int dt = 0; dt < 8; ++dt) {
        bf16x8 vf = *(const bf16x8*)&Vt[cur][(dt * 16 + t16) * 64 +
                                            (((ks * 4 + quad) ^ (t16 & 7)) << 3)];
        Oc[dt] = mfma_bf16(pf, vf, Oc[dt]);
      }
    }
    cur ^= 1;
  }

  if (slot < 0) {
    for (int r = 0; r < 4; ++r) {
      float inv = 1.0f / lrow[r];
      size_t row = (size_t)b * T_SEQ + qt * 64 + w * 16 + quad * 4 + r;
      for (int dt = 0; dt < 8; ++dt)
        out[row * H_DIM + dt * 16 + t16] = Oc[dt][r] * inv;
    }
  } else {
    if (t16 == 0) {
      for (int r = 0; r < 4; ++r) {
        int row = w * 16 + quad * 4 + r;
        MLpart[(size_t)slot * 128 + row * 2 + 0] = mrow[r];
        MLpart[(size_t)slot * 128 + row * 2 + 1] = lrow[r];
      }
    }
    float* op = Opart + (size_t)slot * 8192;
    for (int r = 0; r < 4; ++r) {
      int row = w * 16 + quad * 4 + r;
      for (int dt = 0; dt < 8; ++dt)
        op[row * 128 + dt * 16 + t16] = Oc[dt][r];
    }
  }
}

// ---------------------------------------------------------------------------
// Kernel 4: merge the two key-chunks of each split (b, qt>=32) tile.
// ---------------------------------------------------------------------------
__global__ __launch_bounds__(256) void combine(
    const float* __restrict__ Opart, const float* __restrict__ MLpart,
    float* __restrict__ out)
{
  __shared__ float c1s[64], c2s[64];
  const float L2E = 1.4426950408889634f;
  const int s = blockIdx.x;           // 0..127
  const int b = s >> 5, qt = 32 + (s & 31);
  const int t = threadIdx.x;

  if (t < 64) {
    const float* ML1 = MLpart + (size_t)(s * 2) * 128;
    const float* ML2 = ML1 + 128;
    float m1 = ML1[t * 2], l1 = ML1[t * 2 + 1];
    float m2 = ML2[t * 2], l2 = ML2[t * 2 + 1];
    float m  = fmaxf(m1, m2);
    float e1 = exp2f((m1 - m) * L2E);
    float e2 = exp2f((m2 - m) * L2E);
    float inv = 1.0f / (l1 * e1 + l2 * e2);
    c1s[t] = e1 * inv; c2s[t] = e2 * inv;
  }
  __syncthreads();

  const float* O1 = Opart + (size_t)(s * 2) * 8192;
  const float* O2 = O1 + 8192;
  float* o = out + ((size_t)b * T_SEQ + qt * 64) * (size_t)H_DIM;
  for (int i = t; i < 8192; i += 256) {
    int row = i >> 7;
    o[i] = O1[i] * c1s[row] + O2[i] * c2s[row];
  }
}

// ---------------------------------------------------------------------------
extern "C" void kernel_launch(void* const* d_in, const int* in_sizes, int n_in,
                              void* d_out, int out_size, void* d_ws, size_t ws_size,
                              hipStream_t stream) {
  const float* x  = (const float*)d_in[0];
  const float* Wk = (const float*)d_in[1];
  const float* bk = (const float*)d_in[2];
  const float* Wq = (const float*)d_in[3];
  const float* bq = (const float*)d_in[4];
  const float* Wv = (const float*)d_in[5];
  const float* bv = (const float*)d_in[6];
  float* out = (float*)d_out;

  char* ws = (char*)d_ws;
  u16* qb  = (u16*)(ws);                       // 4 MB  [b][t][128] bf16
  u16* kb  = (u16*)(ws + 4194304);             // 4 MB  [b][t][d'] bf16 (swizzled)
  u16* vT  = (u16*)(ws + 8388608);             // 4 MB  [b][128][t'] bf16 (swizzled)
  u16* Wt  = (u16*)(ws + 12582912);            // 1.5 MB pre-swizzled weights
  float* Opart  = (float*)(ws + 14155776);     // 8 MB  256 x 64 x 128 fp32
  float* MLpart = (float*)(ws + 14155776 + 8388608);   // 128 KB

  const size_t need = 14155776ull + 8388608ull + 131072ull;
  const int split = (ws_size >= need) ? 1 : 0;

  hipLaunchKernelGGL(transpose_w, dim3(32, 2, 3), dim3(256), 0, stream, Wq, Wk, Wv, Wt);
  hipLaunchKernelGGL(qkv_gemm, dim3(128, 3), dim3(256), 0, stream,
                     x, Wt, bq, bk, bv, qb, kb, vT);
  hipLaunchKernelGGL(flash_attn, dim3(4, split ? 96 : 64), dim3(256), 0, stream,
                     qb, kb, vT, out, Opart, MLpart, split);
  if (split)
    hipLaunchKernelGGL(combine, dim3(128), dim3(256), 0, stream, Opart, MLpart, out);
}

// Round 5
// 310.414 us; speedup vs baseline: 1.5471x; 1.0447x over previous
//
#include <hip/hip_runtime.h>
#include <hip/hip_bf16.h>
#include <stdint.h>

#define T_SEQ 4096
#define C_DIM 2048
#define H_DIM 128
#define NBATCH 4

typedef unsigned short u16;
typedef __attribute__((ext_vector_type(8))) __bf16 bf16x8;
typedef __attribute__((ext_vector_type(4))) float f32x4;
typedef __attribute__((ext_vector_type(8))) unsigned short u16x8;

__device__ __forceinline__ u16 f2bf(float f) {
  union { float f; uint32_t i; } v; v.f = f;
  uint32_t r = v.i + 0x7FFFu + ((v.i >> 16) & 1u);
  return (u16)(r >> 16);
}

__device__ __forceinline__ void gload16(const void* g, void* l) {
  __builtin_amdgcn_global_load_lds(
      (__attribute__((address_space(1))) void*)(g),
      (__attribute__((address_space(3))) void*)(l), 16, 0, 0);
}

__device__ __forceinline__ f32x4 mfma_bf16(bf16x8 a, bf16x8 b, f32x4 c) {
  return __builtin_amdgcn_mfma_f32_16x16x32_bf16(a, b, c, 0, 0, 0);
}

// DPP row rotate (16-lane row) reductions — no LDS traffic.
template<int CTRL>
__device__ __forceinline__ float dpp_mov(float x) {
  return __int_as_float(__builtin_amdgcn_mov_dpp(__float_as_int(x), CTRL, 0xF, 0xF, true));
}
__device__ __forceinline__ float red16_max(float v) {
  v = fmaxf(v, dpp_mov<0x121>(v));
  v = fmaxf(v, dpp_mov<0x122>(v));
  v = fmaxf(v, dpp_mov<0x124>(v));
  v = fmaxf(v, dpp_mov<0x128>(v));
  return v;
}
__device__ __forceinline__ float red16_sum(float v) {
  v += dpp_mov<0x121>(v);
  v += dpp_mov<0x122>(v);
  v += dpp_mov<0x124>(v);
  v += dpp_mov<0x128>(v);
  return v;
}

// ---------------------------------------------------------------------------
// Kernel 1: W fp32 [2048][128] -> Wt bf16 [p][n][k], pre-swizzled so that
// contiguous global_load_lds staging lands an XOR-swizzled B-tile in LDS.
// ---------------------------------------------------------------------------
__global__ __launch_bounds__(256) void transpose_w(
    const float* __restrict__ Wq, const float* __restrict__ Wk,
    const float* __restrict__ Wv, u16* __restrict__ Wt)
{
  __shared__ u16 Wl[64 * 72];
  const int bk = blockIdx.x;   // k-tile 0..31
  const int bn = blockIdx.y;   // n-tile 0..1
  const int p  = blockIdx.z;   // 0 q, 1 k, 2 v
  const float* W = (p == 0) ? Wq : (p == 1) ? Wk : Wv;
  const int t = threadIdx.x;

  for (int ps = 0; ps < 16; ++ps) {
    int e  = ps * 256 + t;
    int kk = e >> 6, nn = e & 63;
    Wl[kk * 72 + nn] = f2bf(W[(size_t)(bk * 64 + kk) * H_DIM + bn * 64 + nn]);
  }
  __syncthreads();
  for (int ps = 0; ps < 16; ++ps) {
    int o  = ps * 256 + t;
    int nl = o >> 6, kl = o & 63;
    int n  = bn * 64 + nl;
    int g  = kl >> 3, j = kl & 7;
    int ks = ((g ^ (n & 7)) << 3) | j;
    Wt[(size_t)p * (H_DIM * C_DIM) + (size_t)n * C_DIM + bk * 64 + kl] = Wl[ks * 72 + nl];
  }
}

// ---------------------------------------------------------------------------
// Kernel 2: FUSED QKV GEMM. One block = 64 rows of x, all 384 output cols
// (q|k|v). x read ONCE. 512 threads = 8 waves, wave tile 32x96, BK=64.
// A: fp32 reg-prefetched across K-steps, cvt->ds_write. B: gload16 of
// pre-swizzled Wt. Epilogue: q/k/vT tiles staged in LDS in their exact
// (swizzled) global layouts, then flat 16B coalesced stores.
// ---------------------------------------------------------------------------
__global__ __launch_bounds__(512, 2) void qkv_fused(
    const float* __restrict__ x, const u16* __restrict__ Wt,
    const float* __restrict__ bq, const float* __restrict__ bk, const float* __restrict__ bv,
    u16* __restrict__ qo, u16* __restrict__ ko, u16* __restrict__ vTo)
{
  __shared__ alignas(16) u16 SMEM[28672];   // 56 KB
  u16* As = SMEM;                 // 64 x 64  (8 KB)
  u16* Bs = SMEM + 4096;          // 3 x (128 x 64) (48 KB)

  const int tid  = threadIdx.x;
  const int w    = tid >> 6, lane = tid & 63;
  const int t16  = lane & 15, quad = lane >> 4;
  const int mh   = w >> 2;        // m-half: rows mh*32..+32
  const int nq   = w & 3;         // n-strip: cols nq*96..+96
  const int rt   = blockIdx.x;    // 0..255 row tiles (64 rows each)

  f32x4 acc[2][6];
  for (int i = 0; i < 2; ++i)
    for (int j = 0; j < 6; ++j) acc[i][j] = f32x4{0.f, 0.f, 0.f, 0.f};

  const size_t rowBase = (size_t)rt * 64;
  const int arow = tid >> 3;      // 0..63
  const int ag   = tid & 7;       // 8-float granule
  const float* xrow = &x[(rowBase + arow) * C_DIM + ag * 8];

  // preload first A-chunk into registers
  float4 a0 = ((const float4*)xrow)[0];
  float4 a1 = ((const float4*)xrow)[1];

  for (int k0 = 0; k0 < C_DIM; k0 += 64) {
    __syncthreads();
    // B tiles (3 x 16 KB), pre-swizzled global -> contiguous LDS
    for (int p = 0; p < 3; ++p) {
      const u16* Wp = Wt + (size_t)p * (H_DIM * C_DIM);
      for (int j = 0; j < 2; ++j) {
        int e8 = (((j << 3) + w) * 64 + lane) * 8;
        int rr = e8 >> 6, kk = e8 & 63;
        gload16(Wp + (size_t)rr * C_DIM + k0 + kk, &Bs[p * 8192 + e8]);
      }
    }
    // A: cvt previously-loaded regs -> swizzled ds_write_b128
    {
      u16x8 pk;
      pk[0] = f2bf(a0.x); pk[1] = f2bf(a0.y); pk[2] = f2bf(a0.z); pk[3] = f2bf(a0.w);
      pk[4] = f2bf(a1.x); pk[5] = f2bf(a1.y); pk[6] = f2bf(a1.z); pk[7] = f2bf(a1.w);
      *(u16x8*)&As[arow * 64 + ((ag ^ (arow & 7)) << 3)] = pk;
    }
    // prefetch next A-chunk (drains at next barrier; latency covered)
    if (k0 + 64 < C_DIM) {
      const float4* xp = (const float4*)(xrow + k0 + 64);
      a0 = xp[0]; a1 = xp[1];
    }
    __syncthreads();

    for (int ks = 0; ks < 2; ++ks) {
      bf16x8 af[2], bfr[6];
      for (int ra = 0; ra < 2; ++ra)
        af[ra] = *(const bf16x8*)&As[(mh * 32 + ra * 16 + t16) * 64 +
                                     (((ks * 4 + quad) ^ (t16 & 7)) << 3)];
      for (int c = 0; c < 6; ++c) {
        int col = nq * 96 + c * 16 + t16;
        int p = col >> 7, pc = col & 127;
        bfr[c] = *(const bf16x8*)&Bs[p * 8192 + pc * 64 +
                                     (((ks * 4 + quad) ^ (t16 & 7)) << 3)];
      }
      for (int ra = 0; ra < 2; ++ra)
        for (int c = 0; c < 6; ++c)
          acc[ra][c] = mfma_bf16(af[ra], bfr[c], acc[ra][c]);
    }
  }

  // ---- epilogue: acc -> LDS output tiles in exact global layouts ----
  __syncthreads();
  u16* Oq = SMEM;            // 64 x 128 row-major swizzled
  u16* Ok = SMEM + 8192;     // 64 x 128 row-major swizzled (== global layout)
  u16* Ov = SMEM + 16384;    // 128 x 64 transposed swizzled (== global layout)

  for (int c = 0; c < 6; ++c) {
    int col = nq * 96 + c * 16 + t16;
    int p = col >> 7, pc = col & 127;
    float bias = (p == 0) ? bq[pc] : (p == 1) ? bk[pc] : bv[pc];
    for (int ra = 0; ra < 2; ++ra) {
      for (int r = 0; r < 4; ++r) {
        int row16 = mh * 32 + ra * 16 + quad * 4 + r;   // 0..63
        float v = acc[ra][c][r] + bias;
        if (p == 2) {
          int gt = row16 >> 3;
          Ov[pc * 64 + ((gt ^ (pc & 7)) << 3) + (row16 & 7)] = f2bf(v);
        } else {
          u16* O = (p == 0) ? Oq : Ok;
          int g = pc >> 3;
          O[row16 * 128 + (((g ^ (row16 & 15)) << 3) | (pc & 7))] = f2bf(v);
        }
      }
    }
  }
  __syncthreads();

  // coalesced 16B stores
  const int bb = rt >> 6;            // batch
  const int tb = (rt & 63) * 64;     // t offset within batch (one key-block)
  for (int ps = 0; ps < 2; ++ps) {
    int c = ps * 512 + tid;          // 16B chunk 0..1023
    // q: de-swizzle to natural row-major
    {
      int row16 = c >> 4, g = c & 15;
      u16x8 v = *(const u16x8*)&Oq[row16 * 128 + ((g ^ (row16 & 15)) << 3)];
      *(u16x8*)&qo[(rowBase + row16) * H_DIM + g * 8] = v;
    }
    // k: LDS layout == global layout, flat copy
    *(u16x8*)&ko[rowBase * H_DIM + c * 8] = *(const u16x8*)&Ok[c * 8];
    // vT: LDS layout == global layout per (d, key-block)
    {
      int d = c >> 3, gc = c & 7;
      *(u16x8*)&vTo[((size_t)bb * H_DIM + d) * T_SEQ + tb + gc * 8] =
          *(const u16x8*)&Ov[c * 8];
    }
  }
}

// ---------------------------------------------------------------------------
// Kernel 3: causal flash attention, double-buffered K/V staging, swizzled LDS.
// q natural, k d-swizzled, vT key-swizzled (bf16). Split-K partials fp32.
// ---------------------------------------------------------------------------
__global__ __launch_bounds__(256, 2) void flash_attn(
    const u16* __restrict__ q, const u16* __restrict__ k,
    const u16* __restrict__ vT, float* __restrict__ out,
    float* __restrict__ Opart, float* __restrict__ MLpart, int split)
{
  __shared__ alignas(16) u16 Kt[2][64 * 128];    // 2 x 16 KB
  __shared__ alignas(16) u16 Vt[2][128 * 64];    // 2 x 16 KB
  __shared__ alignas(16) u16 Ps[4 * 16 * 72];    // 9 KB

  const int tid  = threadIdx.x;
  const int w    = tid >> 6, lane = tid & 63;
  const int t16  = lane & 15, quad = lane >> 4;
  const int b    = blockIdx.x;

  int qt, kt0, ktn, slot;   // slot<0 => direct store
  if (split) {
    int bid = blockIdx.y;   // heavy chunks (all batches) dispatch first
    if (bid < 32)      { qt = 32 + bid; kt0 = 0;  ktn = 32;      slot = (b * 32 + bid) * 2; }
    else if (bid < 64) { qt = 95 - bid; kt0 = 32; ktn = qt - 31; slot = (b * 32 + (qt - 32)) * 2 + 1; }
    else               { qt = 95 - bid; kt0 = 0;  ktn = qt + 1;  slot = -1; }
  } else {
    qt = 63 - blockIdx.y; kt0 = 0; ktn = qt + 1; slot = -1;
  }

  const float SCALE = 0.022097086912079612f;   // 2048^-0.5
  const float L2E   = 1.4426950408889634f;

  bf16x8 qf[4];
  {
    const u16* qrow = q + ((size_t)(b * T_SEQ + qt * 64 + w * 16 + t16)) * H_DIM;
    for (int c = 0; c < 4; ++c)
      qf[c] = *(const bf16x8*)(qrow + c * 32 + quad * 8);
  }

  f32x4 Oc[8];
  for (int i = 0; i < 8; ++i) Oc[i] = f32x4{0.f, 0.f, 0.f, 0.f};
  float mrow[4] = {-1e30f, -1e30f, -1e30f, -1e30f};
  float lrow[4] = {0.f, 0.f, 0.f, 0.f};

  const u16* kbase = k  + ((size_t)b * T_SEQ) * H_DIM;
  const u16* vbase = vT + ((size_t)b * H_DIM) * T_SEQ;

  // prefetch first tile into buffer 0
  {
    const u16* kg = kbase + (size_t)(kt0 * 64) * H_DIM;
    for (int j = 0; j < 4; ++j) {
      int e8 = (((j << 2) + w) * 64 + lane) * 8;
      gload16(kg + e8, &Kt[0][e8]);
      int d = e8 >> 6, kk = e8 & 63;
      gload16(vbase + (size_t)d * T_SEQ + kt0 * 64 + kk, &Vt[0][e8]);
    }
  }

  int cur = 0;
  for (int it = 0; it < ktn; ++it) {
    const int kt = kt0 + it;
    __syncthreads();   // drains prefetch of `cur`; WAR-guard for next prefetch
    if (it + 1 < ktn) {
      const int nb = cur ^ 1, ktn1 = kt + 1;
      const u16* kg = kbase + (size_t)(ktn1 * 64) * H_DIM;
      for (int j = 0; j < 4; ++j) {
        int e8 = (((j << 2) + w) * 64 + lane) * 8;
        gload16(kg + e8, &Kt[nb][e8]);
        int d = e8 >> 6, kk = e8 & 63;
        gload16(vbase + (size_t)d * T_SEQ + ktn1 * 64 + kk, &Vt[nb][e8]);
      }
    }

    // S = Q K^T
    f32x4 S[4];
    for (int ct = 0; ct < 4; ++ct) S[ct] = f32x4{0.f, 0.f, 0.f, 0.f};
    for (int c = 0; c < 4; ++c) {
      for (int ct = 0; ct < 4; ++ct) {
        bf16x8 kf = *(const bf16x8*)&Kt[cur][(ct * 16 + t16) * H_DIM +
                                            (((c * 4 + quad) ^ t16) << 3)];
        S[ct] = mfma_bf16(qf[c], kf, S[ct]);
      }
    }

    const bool diag = (kt == qt);
    for (int ct = 0; ct < 4; ++ct)
      for (int r = 0; r < 4; ++r) {
        float s = S[ct][r] * SCALE;
        if (diag && (ct * 16 + t16 > w * 16 + quad * 4 + r)) s = -1e30f;
        S[ct][r] = s;
      }

    float alpha[4], mnew[4];
    for (int r = 0; r < 4; ++r) {
      float mx = red16_max(fmaxf(fmaxf(S[0][r], S[1][r]), fmaxf(S[2][r], S[3][r])));
      mnew[r]  = fmaxf(mrow[r], mx);
      alpha[r] = exp2f((mrow[r] - mnew[r]) * L2E);
      mrow[r]  = mnew[r];
    }
    for (int r = 0; r < 4; ++r) {
      float s = 0.f;
      for (int ct = 0; ct < 4; ++ct) {
        float pv = exp2f((S[ct][r] - mnew[r]) * L2E);
        S[ct][r] = pv;
        s += pv;
      }
      lrow[r] = lrow[r] * alpha[r] + red16_sum(s);
    }
    for (int dt = 0; dt < 8; ++dt)
      for (int r = 0; r < 4; ++r)
        Oc[dt][r] *= alpha[r];

    // P: C layout -> A layout via padded per-wave LDS scratch
    u16* pw = &Ps[w * 1152];
    for (int ct = 0; ct < 4; ++ct)
      for (int r = 0; r < 4; ++r)
        pw[(quad * 4 + r) * 72 + ct * 16 + t16] = f2bf(S[ct][r]);
    __asm__ volatile("s_waitcnt lgkmcnt(0)" ::: "memory");

    for (int ks = 0; ks < 2; ++ks) {
      bf16x8 pf = *(const bf16x8*)&pw[t16 * 72 + ks * 32 + quad * 8];
      for (int dt = 0; dt < 8; ++dt) {
        bf16x8 vf = *(const bf16x8*)&Vt[cur][(dt * 16 + t16) * 64 +
                                            (((ks * 4 + quad) ^ (t16 & 7)) << 3)];
        Oc[dt] = mfma_bf16(pf, vf, Oc[dt]);
      }
    }
    cur ^= 1;
  }

  if (slot < 0) {
    for (int r = 0; r < 4; ++r) {
      float inv = 1.0f / lrow[r];
      size_t row = (size_t)b * T_SEQ + qt * 64 + w * 16 + quad * 4 + r;
      for (int dt = 0; dt < 8; ++dt)
        out[row * H_DIM + dt * 16 + t16] = Oc[dt][r] * inv;
    }
  } else {
    if (t16 == 0) {
      for (int r = 0; r < 4; ++r) {
        int row = w * 16 + quad * 4 + r;
        MLpart[(size_t)slot * 128 + row * 2 + 0] = mrow[r];
        MLpart[(size_t)slot * 128 + row * 2 + 1] = lrow[r];
      }
    }
    float* op = Opart + (size_t)slot * 8192;
    for (int r = 0; r < 4; ++r) {
      int row = w * 16 + quad * 4 + r;
      for (int dt = 0; dt < 8; ++dt)
        op[row * 128 + dt * 16 + t16] = Oc[dt][r];
    }
  }
}

// ---------------------------------------------------------------------------
// Kernel 4: merge the two key-chunks of each split (b, qt>=32) tile.
// ---------------------------------------------------------------------------
__global__ __launch_bounds__(256) void combine(
    const float* __restrict__ Opart, const float* __restrict__ MLpart,
    float* __restrict__ out)
{
  __shared__ float c1s[64], c2s[64];
  const float L2E = 1.4426950408889634f;
  const int s = blockIdx.x;           // 0..127
  const int b = s >> 5, qt = 32 + (s & 31);
  const int t = threadIdx.x;

  if (t < 64) {
    const float* ML1 = MLpart + (size_t)(s * 2) * 128;
    const float* ML2 = ML1 + 128;
    float m1 = ML1[t * 2], l1 = ML1[t * 2 + 1];
    float m2 = ML2[t * 2], l2 = ML2[t * 2 + 1];
    float m  = fmaxf(m1, m2);
    float e1 = exp2f((m1 - m) * L2E);
    float e2 = exp2f((m2 - m) * L2E);
    float inv = 1.0f / (l1 * e1 + l2 * e2);
    c1s[t] = e1 * inv; c2s[t] = e2 * inv;
  }
  __syncthreads();

  const float* O1 = Opart + (size_t)(s * 2) * 8192;
  const float* O2 = O1 + 8192;
  float* o = out + ((size_t)b * T_SEQ + qt * 64) * (size_t)H_DIM;
  for (int i = t; i < 8192; i += 256) {
    int row = i >> 7;
    o[i] = O1[i] * c1s[row] + O2[i] * c2s[row];
  }
}

// ---------------------------------------------------------------------------
extern "C" void kernel_launch(void* const* d_in, const int* in_sizes, int n_in,
                              void* d_out, int out_size, void* d_ws, size_t ws_size,
                              hipStream_t stream) {
  const float* x  = (const float*)d_in[0];
  const float* Wk = (const float*)d_in[1];
  const float* bk = (const float*)d_in[2];
  const float* Wq = (const float*)d_in[3];
  const float* bq = (const float*)d_in[4];
  const float* Wv = (const float*)d_in[5];
  const float* bv = (const float*)d_in[6];
  float* out = (float*)d_out;

  char* ws = (char*)d_ws;
  u16* qb  = (u16*)(ws);                       // 4 MB  [b][t][128] bf16
  u16* kb  = (u16*)(ws + 4194304);             // 4 MB  [b][t][d'] bf16 (swizzled)
  u16* vT  = (u16*)(ws + 8388608);             // 4 MB  [b][128][t'] bf16 (swizzled)
  u16* Wt  = (u16*)(ws + 12582912);            // 1.5 MB pre-swizzled weights
  float* Opart  = (float*)(ws + 14155776);     // 8 MB  256 x 64 x 128 fp32
  float* MLpart = (float*)(ws + 14155776 + 8388608);   // 128 KB

  const size_t need = 14155776ull + 8388608ull + 131072ull;
  const int split = (ws_size >= need) ? 1 : 0;

  hipLaunchKernelGGL(transpose_w, dim3(32, 2, 3), dim3(256), 0, stream, Wq, Wk, Wv, Wt);
  hipLaunchKernelGGL(qkv_fused, dim3(256), dim3(512), 0, stream,
                     x, Wt, bq, bk, bv, qb, kb, vT);
  hipLaunchKernelGGL(flash_attn, dim3(4, split ? 96 : 64), dim3(256), 0, stream,
                     qb, kb, vT, out, Opart, MLpart, split);
  if (split)
    hipLaunchKernelGGL(combine, dim3(128), dim3(256), 0, stream, Opart, MLpart, out);
}

// Round 6
// 295.648 us; speedup vs baseline: 1.6243x; 1.0499x over previous
//
#include <hip/hip_runtime.h>
#include <hip/hip_bf16.h>
#include <stdint.h>

#define T_SEQ 4096
#define C_DIM 2048
#define H_DIM 128
#define NBATCH 4

typedef unsigned short u16;
typedef __attribute__((ext_vector_type(8))) __bf16 bf16x8;
typedef __attribute__((ext_vector_type(4))) float f32x4;
typedef __attribute__((ext_vector_type(8))) unsigned short u16x8;

__device__ __forceinline__ u16 f2bf(float f) {
  union { float f; uint32_t i; } v; v.f = f;
  uint32_t r = v.i + 0x7FFFu + ((v.i >> 16) & 1u);
  return (u16)(r >> 16);
}

__device__ __forceinline__ void gload16(const void* g, void* l) {
  __builtin_amdgcn_global_load_lds(
      (__attribute__((address_space(1))) void*)(g),
      (__attribute__((address_space(3))) void*)(l), 16, 0, 0);
}

__device__ __forceinline__ f32x4 mfma_bf16(bf16x8 a, bf16x8 b, f32x4 c) {
  return __builtin_amdgcn_mfma_f32_16x16x32_bf16(a, b, c, 0, 0, 0);
}

// DPP row rotate (16-lane row) reductions — no LDS traffic.
template<int CTRL>
__device__ __forceinline__ float dpp_mov(float x) {
  return __int_as_float(__builtin_amdgcn_mov_dpp(__float_as_int(x), CTRL, 0xF, 0xF, true));
}
__device__ __forceinline__ float red16_max(float v) {
  v = fmaxf(v, dpp_mov<0x121>(v));
  v = fmaxf(v, dpp_mov<0x122>(v));
  v = fmaxf(v, dpp_mov<0x124>(v));
  v = fmaxf(v, dpp_mov<0x128>(v));
  return v;
}
__device__ __forceinline__ float red16_sum(float v) {
  v += dpp_mov<0x121>(v);
  v += dpp_mov<0x122>(v);
  v += dpp_mov<0x124>(v);
  v += dpp_mov<0x128>(v);
  return v;
}

// ---------------------------------------------------------------------------
// Kernel 1: W fp32 [2048][128] -> Wt bf16 [p][n][k], pre-swizzled so that
// contiguous global_load_lds staging lands an XOR-swizzled B-tile in LDS.
// ---------------------------------------------------------------------------
__global__ __launch_bounds__(256) void transpose_w(
    const float* __restrict__ Wq, const float* __restrict__ Wk,
    const float* __restrict__ Wv, u16* __restrict__ Wt)
{
  __shared__ u16 Wl[64 * 72];
  const int bk = blockIdx.x;   // k-tile 0..31
  const int bn = blockIdx.y;   // n-tile 0..1
  const int p  = blockIdx.z;   // 0 q, 1 k, 2 v
  const float* W = (p == 0) ? Wq : (p == 1) ? Wk : Wv;
  const int t = threadIdx.x;

  for (int ps = 0; ps < 16; ++ps) {
    int e  = ps * 256 + t;
    int kk = e >> 6, nn = e & 63;
    Wl[kk * 72 + nn] = f2bf(W[(size_t)(bk * 64 + kk) * H_DIM + bn * 64 + nn]);
  }
  __syncthreads();
  for (int ps = 0; ps < 16; ++ps) {
    int o  = ps * 256 + t;
    int nl = o >> 6, kl = o & 63;
    int n  = bn * 64 + nl;
    int g  = kl >> 3, j = kl & 7;
    int ks = ((g ^ (n & 7)) << 3) | j;
    Wt[(size_t)p * (H_DIM * C_DIM) + (size_t)n * C_DIM + bk * 64 + kl] = Wl[ks * 72 + nl];
  }
}

// ---------------------------------------------------------------------------
// Kernel 2: FUSED QKV GEMM, single-barrier double-buffered pipeline.
// One block = 64 rows of x, all 384 cols (q|k|v). 512 thr = 8 waves,
// wave tile 32x96, BK=64. Staging for tile i+1 is issued right after the
// barrier and drained at the NEXT barrier — a full compute phase of cover
// (round-5 counters: 2-barrier version paid full latency per iter).
// ---------------------------------------------------------------------------
__global__ __launch_bounds__(512, 1) void qkv_fused(
    const float* __restrict__ x, const u16* __restrict__ Wt,
    const float* __restrict__ bq, const float* __restrict__ bk, const float* __restrict__ bv,
    u16* __restrict__ qo, u16* __restrict__ ko, u16* __restrict__ vTo)
{
  __shared__ alignas(16) u16 SMEM[2][28672];   // 2 x (As 8KB | Bs 48KB) = 112 KB

  const int tid  = threadIdx.x;
  const int w    = tid >> 6, lane = tid & 63;
  const int t16  = lane & 15, quad = lane >> 4;
  const int mh   = w >> 2;        // m-half: rows mh*32..+32
  const int nq   = w & 3;         // n-strip: cols nq*96..+96
  const int rt   = blockIdx.x;    // 0..255 row tiles (64 rows each)

  f32x4 acc[2][6];
  for (int i = 0; i < 2; ++i)
    for (int j = 0; j < 6; ++j) acc[i][j] = f32x4{0.f, 0.f, 0.f, 0.f};

  const size_t rowBase = (size_t)rt * 64;
  const int arow = tid >> 3;      // 0..63
  const int ag   = tid & 7;       // 8-float granule
  const float* xrow = &x[(rowBase + arow) * C_DIM + ag * 8];

  // --- staging helpers (inlined manually below for clarity) ---
  // B tiles: 3 x 16 KB pre-swizzled Wt -> contiguous LDS (6 gload16/thread)
  // A tile:  regs (fp32x8) -> cvt -> one swizzled ds_write_b128/thread

  // Prologue: stage tile 0 into buf 0; preload A-regs for tile 1.
  float4 a0 = ((const float4*)(xrow))[0];
  float4 a1 = ((const float4*)(xrow))[1];
  {
    u16* As = SMEM[0];
    u16* Bs = SMEM[0] + 4096;
    for (int p = 0; p < 3; ++p) {
      const u16* Wp = Wt + (size_t)p * (H_DIM * C_DIM);
      for (int j = 0; j < 2; ++j) {
        int e8 = (((j << 3) + w) * 64 + lane) * 8;
        int rr = e8 >> 6, kk = e8 & 63;
        gload16(Wp + (size_t)rr * C_DIM + kk, &Bs[p * 8192 + e8]);
      }
    }
    u16x8 pk;
    pk[0] = f2bf(a0.x); pk[1] = f2bf(a0.y); pk[2] = f2bf(a0.z); pk[3] = f2bf(a0.w);
    pk[4] = f2bf(a1.x); pk[5] = f2bf(a1.y); pk[6] = f2bf(a1.z); pk[7] = f2bf(a1.w);
    *(u16x8*)&As[arow * 64 + ((ag ^ (arow & 7)) << 3)] = pk;
  }
  a0 = ((const float4*)(xrow + 64))[0];
  a1 = ((const float4*)(xrow + 64))[1];

  for (int it = 0; it < 32; ++it) {
    const int cur = it & 1, nxt = cur ^ 1;
    __syncthreads();   // buf[cur] staging (issued one full iter ago) drains ~free

    if (it + 1 < 32) {
      const int k1 = (it + 1) * 64;
      u16* As = SMEM[nxt];
      u16* Bs = SMEM[nxt] + 4096;
      for (int p = 0; p < 3; ++p) {
        const u16* Wp = Wt + (size_t)p * (H_DIM * C_DIM);
        for (int j = 0; j < 2; ++j) {
          int e8 = (((j << 3) + w) * 64 + lane) * 8;
          int rr = e8 >> 6, kk = e8 & 63;
          gload16(Wp + (size_t)rr * C_DIM + k1 + kk, &Bs[p * 8192 + e8]);
        }
      }
      u16x8 pk;   // a0/a1 were loaded one iter ago — latency covered
      pk[0] = f2bf(a0.x); pk[1] = f2bf(a0.y); pk[2] = f2bf(a0.z); pk[3] = f2bf(a0.w);
      pk[4] = f2bf(a1.x); pk[5] = f2bf(a1.y); pk[6] = f2bf(a1.z); pk[7] = f2bf(a1.w);
      *(u16x8*)&As[arow * 64 + ((ag ^ (arow & 7)) << 3)] = pk;
      if (it + 2 < 32) {
        const float4* xp = (const float4*)(xrow + (it + 2) * 64);
        a0 = xp[0]; a1 = xp[1];
      }
    }

    // compute tile `it` from buf[cur]
    u16* As = SMEM[cur];
    u16* Bs = SMEM[cur] + 4096;
    for (int ks = 0; ks < 2; ++ks) {
      bf16x8 af[2], bfr[6];
      for (int ra = 0; ra < 2; ++ra)
        af[ra] = *(const bf16x8*)&As[(mh * 32 + ra * 16 + t16) * 64 +
                                     (((ks * 4 + quad) ^ (t16 & 7)) << 3)];
      for (int c = 0; c < 6; ++c) {
        int col = nq * 96 + c * 16 + t16;
        int p = col >> 7, pc = col & 127;
        bfr[c] = *(const bf16x8*)&Bs[p * 8192 + pc * 64 +
                                     (((ks * 4 + quad) ^ (t16 & 7)) << 3)];
      }
      for (int ra = 0; ra < 2; ++ra)
        for (int c = 0; c < 6; ++c)
          acc[ra][c] = mfma_bf16(af[ra], bfr[c], acc[ra][c]);
    }
  }

  // ---- epilogue: acc -> LDS output tiles in exact global layouts ----
  __syncthreads();
  u16* Oq = SMEM[0];            // 64 x 128 row-major swizzled
  u16* Ok = SMEM[0] + 8192;     // 64 x 128 row-major swizzled (== global layout)
  u16* Ov = SMEM[0] + 16384;    // 128 x 64 transposed swizzled (== global layout)

  for (int c = 0; c < 6; ++c) {
    int col = nq * 96 + c * 16 + t16;
    int p = col >> 7, pc = col & 127;
    float bias = (p == 0) ? bq[pc] : (p == 1) ? bk[pc] : bv[pc];
    for (int ra = 0; ra < 2; ++ra) {
      for (int r = 0; r < 4; ++r) {
        int row16 = mh * 32 + ra * 16 + quad * 4 + r;   // 0..63
        float v = acc[ra][c][r] + bias;
        if (p == 2) {
          int gt = row16 >> 3;
          Ov[pc * 64 + ((gt ^ (pc & 7)) << 3) + (row16 & 7)] = f2bf(v);
        } else {
          u16* O = (p == 0) ? Oq : Ok;
          int g = pc >> 3;
          O[row16 * 128 + (((g ^ (row16 & 15)) << 3) | (pc & 7))] = f2bf(v);
        }
      }
    }
  }
  __syncthreads();

  // coalesced 16B stores
  const int bb = rt >> 6;            // batch
  const int tb = (rt & 63) * 64;     // t offset within batch (one key-block)
  for (int ps = 0; ps < 2; ++ps) {
    int c = ps * 512 + tid;          // 16B chunk 0..1023
    {
      int row16 = c >> 4, g = c & 15;
      u16x8 v = *(const u16x8*)&Oq[row16 * 128 + ((g ^ (row16 & 15)) << 3)];
      *(u16x8*)&qo[(rowBase + row16) * H_DIM + g * 8] = v;
    }
    *(u16x8*)&ko[rowBase * H_DIM + c * 8] = *(const u16x8*)&Ok[c * 8];
    {
      int d = c >> 3, gc = c & 7;
      *(u16x8*)&vTo[((size_t)bb * H_DIM + d) * T_SEQ + tb + gc * 8] =
          *(const u16x8*)&Ov[c * 8];
    }
  }
}

// ---------------------------------------------------------------------------
// Kernel 3: causal flash attention, double-buffered K/V staging, swizzled LDS.
// q natural, k d-swizzled, vT key-swizzled (bf16). Split-K partials fp32.
// ---------------------------------------------------------------------------
__global__ __launch_bounds__(256, 2) void flash_attn(
    const u16* __restrict__ q, const u16* __restrict__ k,
    const u16* __restrict__ vT, float* __restrict__ out,
    float* __restrict__ Opart, float* __restrict__ MLpart, int split)
{
  __shared__ alignas(16) u16 Kt[2][64 * 128];    // 2 x 16 KB
  __shared__ alignas(16) u16 Vt[2][128 * 64];    // 2 x 16 KB
  __shared__ alignas(16) u16 Ps[4 * 16 * 72];    // 9 KB

  const int tid  = threadIdx.x;
  const int w    = tid >> 6, lane = tid & 63;
  const int t16  = lane & 15, quad = lane >> 4;
  const int b    = blockIdx.x;

  int qt, kt0, ktn, slot;   // slot<0 => direct store
  if (split) {
    int bid = blockIdx.y;   // heavy chunks (all batches) dispatch first
    if (bid < 32)      { qt = 32 + bid; kt0 = 0;  ktn = 32;      slot = (b * 32 + bid) * 2; }
    else if (bid < 64) { qt = 95 - bid; kt0 = 32; ktn = qt - 31; slot = (b * 32 + (qt - 32)) * 2 + 1; }
    else               { qt = 95 - bid; kt0 = 0;  ktn = qt + 1;  slot = -1; }
  } else {
    qt = 63 - blockIdx.y; kt0 = 0; ktn = qt + 1; slot = -1;
  }

  const float SCALE = 0.022097086912079612f;   // 2048^-0.5
  const float L2E   = 1.4426950408889634f;

  bf16x8 qf[4];
  {
    const u16* qrow = q + ((size_t)(b * T_SEQ + qt * 64 + w * 16 + t16)) * H_DIM;
    for (int c = 0; c < 4; ++c)
      qf[c] = *(const bf16x8*)(qrow + c * 32 + quad * 8);
  }

  f32x4 Oc[8];
  for (int i = 0; i < 8; ++i) Oc[i] = f32x4{0.f, 0.f, 0.f, 0.f};
  float mrow[4] = {-1e30f, -1e30f, -1e30f, -1e30f};
  float lrow[4] = {0.f, 0.f, 0.f, 0.f};

  const u16* kbase = k  + ((size_t)b * T_SEQ) * H_DIM;
  const u16* vbase = vT + ((size_t)b * H_DIM) * T_SEQ;

  // prefetch first tile into buffer 0
  {
    const u16* kg = kbase + (size_t)(kt0 * 64) * H_DIM;
    for (int j = 0; j < 4; ++j) {
      int e8 = (((j << 2) + w) * 64 + lane) * 8;
      gload16(kg + e8, &Kt[0][e8]);
      int d = e8 >> 6, kk = e8 & 63;
      gload16(vbase + (size_t)d * T_SEQ + kt0 * 64 + kk, &Vt[0][e8]);
    }
  }

  int cur = 0;
  for (int it = 0; it < ktn; ++it) {
    const int kt = kt0 + it;
    __syncthreads();   // drains prefetch of `cur`; WAR-guard for next prefetch
    if (it + 1 < ktn) {
      const int nb = cur ^ 1, ktn1 = kt + 1;
      const u16* kg = kbase + (size_t)(ktn1 * 64) * H_DIM;
      for (int j = 0; j < 4; ++j) {
        int e8 = (((j << 2) + w) * 64 + lane) * 8;
        gload16(kg + e8, &Kt[nb][e8]);
        int d = e8 >> 6, kk = e8 & 63;
        gload16(vbase + (size_t)d * T_SEQ + ktn1 * 64 + kk, &Vt[nb][e8]);
      }
    }

    // S = Q K^T
    f32x4 S[4];
    for (int ct = 0; ct < 4; ++ct) S[ct] = f32x4{0.f, 0.f, 0.f, 0.f};
    for (int c = 0; c < 4; ++c) {
      for (int ct = 0; ct < 4; ++ct) {
        bf16x8 kf = *(const bf16x8*)&Kt[cur][(ct * 16 + t16) * H_DIM +
                                            (((c * 4 + quad) ^ t16) << 3)];
        S[ct] = mfma_bf16(qf[c], kf, S[ct]);
      }
    }

    const bool diag = (kt == qt);
    for (int ct = 0; ct < 4; ++ct)
      for (int r = 0; r < 4; ++r) {
        float s = S[ct][r] * SCALE;
        if (diag && (ct * 16 + t16 > w * 16 + quad * 4 + r)) s = -1e30f;
        S[ct][r] = s;
      }

    float alpha[4], mnew[4];
    for (int r = 0; r < 4; ++r) {
      float mx = red16_max(fmaxf(fmaxf(S[0][r], S[1][r]), fmaxf(S[2][r], S[3][r])));
      mnew[r]  = fmaxf(mrow[r], mx);
      alpha[r] = exp2f((mrow[r] - mnew[r]) * L2E);
      mrow[r]  = mnew[r];
    }
    for (int r = 0; r < 4; ++r) {
      float s = 0.f;
      for (int ct = 0; ct < 4; ++ct) {
        float pv = exp2f((S[ct][r] - mnew[r]) * L2E);
        S[ct][r] = pv;
        s += pv;
      }
      lrow[r] = lrow[r] * alpha[r] + red16_sum(s);
    }
    for (int dt = 0; dt < 8; ++dt)
      for (int r = 0; r < 4; ++r)
        Oc[dt][r] *= alpha[r];

    // P: C layout -> A layout via padded per-wave LDS scratch
    u16* pw = &Ps[w * 1152];
    for (int ct = 0; ct < 4; ++ct)
      for (int r = 0; r < 4; ++r)
        pw[(quad * 4 + r) * 72 + ct * 16 + t16] = f2bf(S[ct][r]);
    __asm__ volatile("s_waitcnt lgkmcnt(0)" ::: "memory");

    for (int ks = 0; ks < 2; ++ks) {
      bf16x8 pf = *(const bf16x8*)&pw[t16 * 72 + ks * 32 + quad * 8];
      for (int dt = 0; dt < 8; ++dt) {
        bf16x8 vf = *(const bf16x8*)&Vt[cur][(dt * 16 + t16) * 64 +
                                            (((ks * 4 + quad) ^ (t16 & 7)) << 3)];
        Oc[dt] = mfma_bf16(pf, vf, Oc[dt]);
      }
    }
    cur ^= 1;
  }

  if (slot < 0) {
    for (int r = 0; r < 4; ++r) {
      float inv = 1.0f / lrow[r];
      size_t row = (size_t)b * T_SEQ + qt * 64 + w * 16 + quad * 4 + r;
      for (int dt = 0; dt < 8; ++dt)
        out[row * H_DIM + dt * 16 + t16] = Oc[dt][r] * inv;
    }
  } else {
    if (t16 == 0) {
      for (int r = 0; r < 4; ++r) {
        int row = w * 16 + quad * 4 + r;
        MLpart[(size_t)slot * 128 + row * 2 + 0] = mrow[r];
        MLpart[(size_t)slot * 128 + row * 2 + 1] = lrow[r];
      }
    }
    float* op = Opart + (size_t)slot * 8192;
    for (int r = 0; r < 4; ++r) {
      int row = w * 16 + quad * 4 + r;
      for (int dt = 0; dt < 8; ++dt)
        op[row * 128 + dt * 16 + t16] = Oc[dt][r];
    }
  }
}

// ---------------------------------------------------------------------------
// Kernel 4: merge the two key-chunks of each split (b, qt>=32) tile.
// ---------------------------------------------------------------------------
__global__ __launch_bounds__(256) void combine(
    const float* __restrict__ Opart, const float* __restrict__ MLpart,
    float* __restrict__ out)
{
  __shared__ float c1s[64], c2s[64];
  const float L2E = 1.4426950408889634f;
  const int s = blockIdx.x;           // 0..127
  const int b = s >> 5, qt = 32 + (s & 31);
  const int t = threadIdx.x;

  if (t < 64) {
    const float* ML1 = MLpart + (size_t)(s * 2) * 128;
    const float* ML2 = ML1 + 128;
    float m1 = ML1[t * 2], l1 = ML1[t * 2 + 1];
    float m2 = ML2[t * 2], l2 = ML2[t * 2 + 1];
    float m  = fmaxf(m1, m2);
    float e1 = exp2f((m1 - m) * L2E);
    float e2 = exp2f((m2 - m) * L2E);
    float inv = 1.0f / (l1 * e1 + l2 * e2);
    c1s[t] = e1 * inv; c2s[t] = e2 * inv;
  }
  __syncthreads();

  const float* O1 = Opart + (size_t)(s * 2) * 8192;
  const float* O2 = O1 + 8192;
  float* o = out + ((size_t)b * T_SEQ + qt * 64) * (size_t)H_DIM;
  for (int i = t; i < 8192; i += 256) {
    int row = i >> 7;
    o[i] = O1[i] * c1s[row] + O2[i] * c2s[row];
  }
}

// ---------------------------------------------------------------------------
extern "C" void kernel_launch(void* const* d_in, const int* in_sizes, int n_in,
                              void* d_out, int out_size, void* d_ws, size_t ws_size,
                              hipStream_t stream) {
  const float* x  = (const float*)d_in[0];
  const float* Wk = (const float*)d_in[1];
  const float* bk = (const float*)d_in[2];
  const float* Wq = (const float*)d_in[3];
  const float* bq = (const float*)d_in[4];
  const float* Wv = (const float*)d_in[5];
  const float* bv = (const float*)d_in[6];
  float* out = (float*)d_out;

  char* ws = (char*)d_ws;
  u16* qb  = (u16*)(ws);                       // 4 MB  [b][t][128] bf16
  u16* kb  = (u16*)(ws + 4194304);             // 4 MB  [b][t][d'] bf16 (swizzled)
  u16* vT  = (u16*)(ws + 8388608);             // 4 MB  [b][128][t'] bf16 (swizzled)
  u16* Wt  = (u16*)(ws + 12582912);            // 1.5 MB pre-swizzled weights
  float* Opart  = (float*)(ws + 14155776);     // 8 MB  256 x 64 x 128 fp32
  float* MLpart = (float*)(ws + 14155776 + 8388608);   // 128 KB

  const size_t need = 14155776ull + 8388608ull + 131072ull;
  const int split = (ws_size >= need) ? 1 : 0;

  hipLaunchKernelGGL(transpose_w, dim3(32, 2, 3), dim3(256), 0, stream, Wq, Wk, Wv, Wt);
  hipLaunchKernelGGL(qkv_fused, dim3(256), dim3(512), 0, stream,
                     x, Wt, bq, bk, bv, qb, kb, vT);
  hipLaunchKernelGGL(flash_attn, dim3(4, split ? 96 : 64), dim3(256), 0, stream,
                     qb, kb, vT, out, Opart, MLpart, split);
  if (split)
    hipLaunchKernelGGL(combine, dim3(128), dim3(256), 0, stream, Opart, MLpart, out);
}